// Round 2
// baseline (360.141 us; speedup 1.0000x reference)
//
#include <hip/hip_runtime.h>
#include <hip/hip_bf16.h>

#define L_SEQ  2048
#define EMB    1024
#define NHEAD  16
#define HDIM   64
#define NBATCH 2

typedef unsigned short u16;
typedef short bf16x8 __attribute__((ext_vector_type(8)));
typedef float f32x4  __attribute__((ext_vector_type(4)));

static __device__ __forceinline__ u16 f2bf(float x) {
    union { float f; unsigned u; } a; a.f = x;
    unsigned r = a.u + 0x7FFFu + ((a.u >> 16) & 1u);
    return (u16)(r >> 16);
}

// ---------------------------------------------------------------------------
// Flash attention: one block = (n, h, 64 q-rows); 4 waves x 16 q-rows.
// K-tile = 32. Inputs fp32 -> bf16 during staging. S = (Q/8) K^T via
// mfma 16x16x32 bf16; online softmax in fp32; P -> per-wave LDS round trip
// (C-layout -> A-layout); O += P V. Output: bf16 workspace for the GEMM.
// ---------------------------------------------------------------------------
__global__ __launch_bounds__(256, 2)
void attn_kernel(const float* __restrict__ Vg, const float* __restrict__ Kg,
                 const float* __restrict__ Qg, const int* __restrict__ Mg,
                 u16* __restrict__ Og)
{
    const int qblk = blockIdx.x;
    const int h    = blockIdx.y;
    const int n    = blockIdx.z;
    const int tid  = threadIdx.x;
    const int wave = tid >> 6;
    const int lane = tid & 63;
    const int l16  = lane & 15;
    const int quad = lane >> 4;

    // padded rows (stride in u16): 72*2=144B, 40*2=80B — 16B multiples
    __shared__ u16 Kl[32][72];      // [k_row][d]
    __shared__ u16 Vl[64][40];      // [d][k_row]  (transposed)
    __shared__ u16 Pl[4][16][40];   // per-wave [q][k_row]

    const int q0 = qblk * 64 + wave * 16;

    // Q fragments, A-layout: A[m=l16][k=quad*8+j], pre-scaled by 1/sqrt(64)
    bf16x8 qf[2];
    {
        const float* qp = Qg + ((size_t)(n * L_SEQ) + q0 + l16) * EMB + h * HDIM;
        #pragma unroll
        for (int hh = 0; hh < 2; ++hh)
            #pragma unroll
            for (int j = 0; j < 8; ++j)
                qf[hh][j] = (short)f2bf(qp[hh * 32 + quad * 8 + j] * 0.125f);
    }

    f32x4 acc[4];
    #pragma unroll
    for (int c = 0; c < 4; ++c)
        #pragma unroll
        for (int r = 0; r < 4; ++r) acc[c][r] = 0.f;
    float mrow[4], lrow[4];
    #pragma unroll
    for (int r = 0; r < 4; ++r) { mrow[r] = -3.0e38f; lrow[r] = 0.f; }

    const float* kbase = Kg + (size_t)(n * L_SEQ) * EMB + h * HDIM;
    const float* vbase = Vg + (size_t)(n * L_SEQ) * EMB + h * HDIM;
    const int*   mbase = Mg + (size_t)n * L_SEQ * L_SEQ;

    const int srow = tid >> 3;        // 0..31  (k-row within tile)
    const int scol = (tid & 7) * 8;   // 0..56  (d, 8 floats per thread)

    for (int k0 = 0; k0 < L_SEQ; k0 += 32) {
        // ---- load fp32, convert to bf16 ----
        const float* kp = kbase + (size_t)(k0 + srow) * EMB + scol;
        const float* vp = vbase + (size_t)(k0 + srow) * EMB + scol;
        float4 k0v = *(const float4*)(kp);
        float4 k1v = *(const float4*)(kp + 4);
        float4 v0v = *(const float4*)(vp);
        float4 v1v = *(const float4*)(vp + 4);
        u16 kb[8], vb[8];
        kb[0]=f2bf(k0v.x); kb[1]=f2bf(k0v.y); kb[2]=f2bf(k0v.z); kb[3]=f2bf(k0v.w);
        kb[4]=f2bf(k1v.x); kb[5]=f2bf(k1v.y); kb[6]=f2bf(k1v.z); kb[7]=f2bf(k1v.w);
        vb[0]=f2bf(v0v.x); vb[1]=f2bf(v0v.y); vb[2]=f2bf(v0v.z); vb[3]=f2bf(v0v.w);
        vb[4]=f2bf(v1v.x); vb[5]=f2bf(v1v.y); vb[6]=f2bf(v1v.z); vb[7]=f2bf(v1v.w);

        __syncthreads();   // prior tile's LDS reads done
        *(uint4*)&Kl[srow][scol] = *(const uint4*)kb;
        #pragma unroll
        for (int j = 0; j < 8; ++j) Vl[scol + j][srow] = vb[j];
        __syncthreads();

        // ---- S = (Q/8) K^T : 16 x 32, two 16-col chunks ----
        f32x4 S[2];
        #pragma unroll
        for (int c = 0; c < 2; ++c) {
            bf16x8 b0 = *(const bf16x8*)&Kl[c * 16 + l16][quad * 8];
            bf16x8 b1 = *(const bf16x8*)&Kl[c * 16 + l16][32 + quad * 8];
            f32x4 z;
            z[0] = 0.f; z[1] = 0.f; z[2] = 0.f; z[3] = 0.f;
            z = __builtin_amdgcn_mfma_f32_16x16x32_bf16(qf[0], b0, z, 0, 0, 0);
            z = __builtin_amdgcn_mfma_f32_16x16x32_bf16(qf[1], b1, z, 0, 0, 0);
            S[c] = z;
        }

        // ---- mask (C-layout: row = quad*4+r, col = c*16+l16) ----
        #pragma unroll
        for (int c = 0; c < 2; ++c) {
            const int* mp = mbase + (size_t)(q0 + quad * 4) * L_SEQ + k0 + c * 16 + l16;
            #pragma unroll
            for (int r = 0; r < 4; ++r)
                if (mp[(size_t)r * L_SEQ] == 0) S[c][r] = -1.0e20f;
        }

        // ---- online softmax (rows live in 16-lane quads) ----
        #pragma unroll
        for (int r = 0; r < 4; ++r) {
            float v = fmaxf(S[0][r], S[1][r]);
            v = fmaxf(v, __shfl_xor(v, 1));
            v = fmaxf(v, __shfl_xor(v, 2));
            v = fmaxf(v, __shfl_xor(v, 4));
            v = fmaxf(v, __shfl_xor(v, 8));
            float mn    = fmaxf(mrow[r], v);
            float alpha = __expf(mrow[r] - mn);
            float p0 = __expf(S[0][r] - mn);
            float p1 = __expf(S[1][r] - mn);
            S[0][r] = p0; S[1][r] = p1;
            float s = p0 + p1;
            s += __shfl_xor(s, 1);
            s += __shfl_xor(s, 2);
            s += __shfl_xor(s, 4);
            s += __shfl_xor(s, 8);
            lrow[r] = lrow[r] * alpha + s;
            mrow[r] = mn;
            #pragma unroll
            for (int c = 0; c < 4; ++c) acc[c][r] *= alpha;
        }

        // ---- P: C-layout -> LDS -> A-layout (in-wave round trip) ----
        #pragma unroll
        for (int c = 0; c < 2; ++c)
            #pragma unroll
            for (int r = 0; r < 4; ++r)
                Pl[wave][quad * 4 + r][c * 16 + l16] = f2bf(S[c][r]);

        // HW wait for the ds_writes AND a compiler reordering fence
        asm volatile("s_waitcnt lgkmcnt(0)" ::: "memory");

        bf16x8 pf = *(const bf16x8*)&Pl[wave][l16][quad * 8];
        #pragma unroll
        for (int c = 0; c < 4; ++c) {
            bf16x8 vf = *(const bf16x8*)&Vl[c * 16 + l16][quad * 8];
            acc[c] = __builtin_amdgcn_mfma_f32_16x16x32_bf16(pf, vf, acc[c], 0, 0, 0);
        }
    }

    // ---- epilogue: O /= l, bf16 to workspace [n][q][h*64+d] ----
    #pragma unroll
    for (int r = 0; r < 4; ++r) {
        float inv = 1.f / lrow[r];
        u16* op = Og + ((size_t)(n * L_SEQ) + q0 + quad * 4 + r) * EMB + h * HDIM;
        #pragma unroll
        for (int c = 0; c < 4; ++c)
            op[c * 16 + l16] = f2bf(acc[c][r] * inv);
    }
}

// ---------------------------------------------------------------------------
// out(fp32) = attn(4096x1024 bf16 ws) @ W^T + b.  W fp32 row-major (E,E).
// 128x128 block tile, 4 waves each 64x64, K-step 32.
// ---------------------------------------------------------------------------
__global__ __launch_bounds__(256, 2)
void out_gemm(const u16* __restrict__ A, const float* __restrict__ W,
              const float* __restrict__ bias, float* __restrict__ out)
{
    const int bn  = blockIdx.x;   // 0..7
    const int bm  = blockIdx.y;   // 0..31
    const int tid = threadIdx.x;
    const int wave = tid >> 6;
    const int lane = tid & 63;
    const int l16  = lane & 15;
    const int quad = lane >> 4;
    const int wr = wave >> 1, wc = wave & 1;

    __shared__ u16 Al[128][40];   // [m][k] bf16, 80B rows
    __shared__ u16 Wl[128][40];   // [e][k] bf16

    f32x4 acc[4][4];
    #pragma unroll
    for (int i = 0; i < 4; ++i)
        #pragma unroll
        for (int j = 0; j < 4; ++j)
            #pragma unroll
            for (int r = 0; r < 4; ++r) acc[i][j][r] = 0.f;

    const int srow = tid >> 1;         // 0..127
    const int scol = (tid & 1) * 16;   // 0 or 16 (elements of the 32-wide K-step)

    const u16*   ap = A + (size_t)(bm * 128 + srow) * EMB + scol;
    const float* wp = W + (size_t)(bn * 128 + srow) * EMB + scol;

    for (int k0 = 0; k0 < EMB; k0 += 32) {
        uint4 av0 = *(const uint4*)(ap + k0);       // 8 bf16
        uint4 av1 = *(const uint4*)(ap + k0 + 8);   // 8 bf16
        float4 w0 = *(const float4*)(wp + k0);
        float4 w1 = *(const float4*)(wp + k0 + 4);
        float4 w2 = *(const float4*)(wp + k0 + 8);
        float4 w3 = *(const float4*)(wp + k0 + 12);
        u16 wb[16];
        wb[0]=f2bf(w0.x);  wb[1]=f2bf(w0.y);  wb[2]=f2bf(w0.z);  wb[3]=f2bf(w0.w);
        wb[4]=f2bf(w1.x);  wb[5]=f2bf(w1.y);  wb[6]=f2bf(w1.z);  wb[7]=f2bf(w1.w);
        wb[8]=f2bf(w2.x);  wb[9]=f2bf(w2.y);  wb[10]=f2bf(w2.z); wb[11]=f2bf(w2.w);
        wb[12]=f2bf(w3.x); wb[13]=f2bf(w3.y); wb[14]=f2bf(w3.z); wb[15]=f2bf(w3.w);

        __syncthreads();
        *(uint4*)&Al[srow][scol]     = av0;
        *(uint4*)&Al[srow][scol + 8] = av1;
        *(uint4*)&Wl[srow][scol]     = *(const uint4*)&wb[0];
        *(uint4*)&Wl[srow][scol + 8] = *(const uint4*)&wb[8];
        __syncthreads();

        bf16x8 af[4], bfr[4];
        #pragma unroll
        for (int i = 0; i < 4; ++i)
            af[i] = *(const bf16x8*)&Al[wr * 64 + i * 16 + l16][quad * 8];
        #pragma unroll
        for (int j = 0; j < 4; ++j)
            bfr[j] = *(const bf16x8*)&Wl[wc * 64 + j * 16 + l16][quad * 8];
        #pragma unroll
        for (int i = 0; i < 4; ++i)
            #pragma unroll
            for (int j = 0; j < 4; ++j)
                acc[i][j] = __builtin_amdgcn_mfma_f32_16x16x32_bf16(af[i], bfr[j], acc[i][j], 0, 0, 0);
    }

    #pragma unroll
    for (int j = 0; j < 4; ++j) {
        int col = bn * 128 + wc * 64 + j * 16 + l16;
        float bv = bias[col];
        #pragma unroll
        for (int i = 0; i < 4; ++i) {
            int row0 = bm * 128 + wr * 64 + i * 16 + quad * 4;
            #pragma unroll
            for (int r = 0; r < 4; ++r)
                out[(size_t)(row0 + r) * EMB + col] = acc[i][j][r] + bv;
        }
    }
}

extern "C" void kernel_launch(void* const* d_in, const int* in_sizes, int n_in,
                              void* d_out, int out_size, void* d_ws, size_t ws_size,
                              hipStream_t stream)
{
    const float* Vg = (const float*)d_in[0];
    const float* Kg = (const float*)d_in[1];
    const float* Qg = (const float*)d_in[2];
    const int*   Mg = (const int*)d_in[3];
    const float* Wg = (const float*)d_in[4];
    const float* Bg = (const float*)d_in[5];
    float* Og = (float*)d_out;
    u16* attn_ws = (u16*)d_ws;   // (N*L, E) bf16 = 8 MB

    dim3 g1(L_SEQ / 64, NHEAD, NBATCH);
    attn_kernel<<<g1, 256, 0, stream>>>(Vg, Kg, Qg, Mg, attn_ws);

    dim3 g2(EMB / 128, (NBATCH * L_SEQ) / 128);
    out_gemm<<<g2, 256, 0, stream>>>(attn_ws, Wg, Bg, Og);
}